// Round 9
// baseline (315.462 us; speedup 1.0000x reference)
//
#include <hip/hip_runtime.h>

#define N_NODES 100000
#define N_EDGES 3200000
#define F_IN 128
#define F_OUT 16

#define NSEG 512                 // binning segments (R9: 256->512 for k_bin occupancy)
#define EPS (N_EDGES / NSEG)     // 6250 edges/segment (exact)
#define NBUCK 2048               // destination buckets
#define NPB 49                   // nodes per bucket: 49*2048 = 100352 >= N
#define GEMM_BLOCKS ((N_NODES + 15) / 16)   // 6250
#define MAXREC 2048              // staged records per bucket (mean 1563, +12 sigma)

// ---- ws layout (bytes) ----
// Tt (NBUCK*NSEG ints = 4 MB) ALIASES the g region: g is written only in k_sort,
// strictly after k_bin's last Tt read (hist->scan->bin read Tt; sort overwrites).
#define OFF_NCNT  0u            // N ints (400 KB), written by k_sort
#define OFF_TOT   0x200000u     // NBUCK ints
#define OFF_BASE  0x202000u     // NBUCK ints
#define OFF_DINV  0x210000u     // N floats (400 KB)
#define OFF_NPTR  0x280000u     // N ints (400 KB)
#define OFF_HH    0x300000u     // N*16 floats (6.4 MB)
#define OFF_GG    0x920000u     // N*16 floats (6.4 MB)
#define OFF_TT    0x920000u     // aliases GG (4 MB < 7.2 MB available)
#define OFF_CSR   0x1000000u    // E int2 (25.6 MB); sorted IN PLACE by k_sort
#define WS_NEEDED ((size_t)0x1000000 + (size_t)N_EDGES * 8)

// ============ main path (no global atomics) ============

// K1: per-segment LDS histogram of dest buckets  +  co-scheduled h = x@W
__global__ void k_hist_gemm(const int* __restrict__ col,
                            int* __restrict__ Tt,
                            const float* __restrict__ x,
                            const float* __restrict__ W,
                            float* __restrict__ h) {
    __shared__ int smem[2048];   // hist bins OR 8KB W staging
    int tid = threadIdx.x;
    if (blockIdx.x < NSEG) {
        int s = blockIdx.x;
        for (int i = tid; i < NBUCK; i += 256) smem[i] = 0;
        __syncthreads();
        int e0 = s * EPS;
        for (int i = tid; i < EPS; i += 256)
            atomicAdd(&smem[col[e0 + i] / NPB], 1);
        __syncthreads();
        for (int i = tid; i < NBUCK; i += 256)
            Tt[(size_t)i * NSEG + s] = smem[i];
    } else {
        float* Ws = (float*)smem;
        for (int i = tid; i < F_IN * F_OUT; i += 256) Ws[i] = W[i];
        __syncthreads();
        int n = (blockIdx.x - NSEG) * 16 + (tid >> 4);
        int j = tid & 15;
        if (n >= N_NODES) return;
        const float4* xr = (const float4*)(x + (size_t)n * F_IN);
        float acc = 0.0f;
#pragma unroll
        for (int k4 = 0; k4 < F_IN / 4; ++k4) {
            float4 xv = xr[k4];
            int k = k4 * 4;
            acc += xv.x * Ws[(k + 0) * F_OUT + j];
            acc += xv.y * Ws[(k + 1) * F_OUT + j];
            acc += xv.z * Ws[(k + 2) * F_OUT + j];
            acc += xv.w * Ws[(k + 3) * F_OUT + j];
        }
        h[(size_t)n * F_OUT + j] = acc;
    }
}

// K2: wave per bucket — exclusive scan of its NSEG=512 counts (two 256-halves
// with carry, int4 coalesced)
__global__ void k_scan_a(int* __restrict__ Tt, int* __restrict__ tot) {
    int tid = threadIdx.x;
    int b = blockIdx.x * 4 + (tid >> 6);     // 4 waves/block
    int l = tid & 63;
    int4* row = (int4*)Tt + (size_t)b * (NSEG / 4);
    int4 v0 = row[l];
    int4 v1 = row[l + 64];
    int s0 = v0.x + v0.y + v0.z + v0.w;
    int inc0 = s0;
    for (int off = 1; off < 64; off <<= 1) {
        int t = __shfl_up(inc0, off);
        if (l >= off) inc0 += t;
    }
    int exc0 = inc0 - s0;
    int tot0 = __shfl(inc0, 63);
    int s1 = v1.x + v1.y + v1.z + v1.w;
    int inc1 = s1;
    for (int off = 1; off < 64; off <<= 1) {
        int t = __shfl_up(inc1, off);
        if (l >= off) inc1 += t;
    }
    int exc1 = inc1 - s1 + tot0;
    int4 o0, o1;
    o0.x = exc0;
    o0.y = exc0 + v0.x;
    o0.z = o0.y + v0.y;
    o0.w = o0.z + v0.z;
    o1.x = exc1;
    o1.y = exc1 + v1.x;
    o1.z = o1.y + v1.y;
    o1.w = o1.z + v1.z;
    row[l] = o0;
    row[l + 64] = o1;
    if (l == 63) tot[b] = inc1 + tot0;
}

// K3: single block — exclusive scan of NBUCK totals -> base
__global__ void k_scan_b(const int* __restrict__ tot, int* __restrict__ base) {
    __shared__ int s[256];
    int tid = threadIdx.x;
    const int4* t4 = (const int4*)tot;
    int4 p = t4[tid * 2], q = t4[tid * 2 + 1];
    int lsum = p.x + p.y + p.z + p.w + q.x + q.y + q.z + q.w;
    s[tid] = lsum;
    __syncthreads();
    for (int off = 1; off < 256; off <<= 1) {
        int t = (tid >= off) ? s[tid - off] : 0;
        __syncthreads();
        s[tid] += t;
        __syncthreads();
    }
    int run = s[tid] - lsum;
    int4 o1, o2;
    o1.x = run; run += p.x;
    o1.y = run; run += p.y;
    o1.z = run; run += p.z;
    o1.w = run; run += p.w;
    o2.x = run; run += q.x;
    o2.y = run; run += q.y;
    o2.z = run; run += q.z;
    o2.w = run;
    int4* b4 = (int4*)base;
    b4[tid * 2] = o1;
    b4[tid * 2 + 1] = o2;
}

// K4: per-segment binning via LDS cursors; records: ((r<<7)|c_local, ew)
__global__ void __launch_bounds__(512) k_bin(const int* __restrict__ row,
                                             const int* __restrict__ col,
                                             const float* __restrict__ ew,
                                             const int* __restrict__ Tt,
                                             const int* __restrict__ base,
                                             int2* __restrict__ csr) {
    __shared__ int cur[NBUCK];
    int tid = threadIdx.x;
    int s = blockIdx.x;
    for (int i = tid; i < NBUCK; i += 512)
        cur[i] = base[i] + Tt[(size_t)i * NSEG + s];
    __syncthreads();
    int e0 = s * EPS;
    for (int i = tid; i < EPS; i += 512) {
        int e = e0 + i;
        int r = row[e];
        int c = col[e];
        int bk = c / NPB;
        int pos = atomicAdd(&cur[bk], 1);      // LDS atomic
        int2 rec;
        rec.x = (r << 7) | (c - bk * NPB);
        rec.y = __float_as_int(ew[e]);
        csr[pos] = rec;
    }
}

// K5: per-bucket — stage slice to LDS; per-node count + weight-sum; scan;
// dinv + g = dinv*h; nodeptr/ncnt; IN-PLACE scatter sorted by dest node,
// stripping c_local (records become (r, w)). Overflow buckets (> MAXREC,
// statistically never) are left unsorted and flagged via negative ncnt.
__global__ void k_sort(const int* __restrict__ base,
                       const int* __restrict__ tot,
                       int2* __restrict__ csr,
                       const float* __restrict__ h,
                       float* __restrict__ dinv,
                       float* __restrict__ g,
                       int* __restrict__ nodeptr,
                       int* __restrict__ ncnt) {
    __shared__ int2 srec[MAXREC];      // 16 KB
    __shared__ int cnt[NPB];
    __shared__ float wsum[NPB];
    __shared__ int cur[NPB];
    __shared__ float dl[NPB];
    int tid = threadIdx.x;
    int b = blockIdx.x;
    int c0 = b * NPB;
    int bseg = base[b];
    int total = tot[b];
    bool ovf = (total > MAXREC);
    int nstage = ovf ? MAXREC : total;

    if (tid < NPB) { cnt[tid] = 0; wsum[tid] = 1.0f; }   // self-loop weight
    __syncthreads();

    // stage + count (remainder counted from global)
    for (int i = tid; i < nstage; i += 256) {
        int2 rec = csr[bseg + i];
        srec[i] = rec;
        atomicAdd(&cnt[rec.x & 127], 1);
        atomicAdd(&wsum[rec.x & 127], __int_as_float(rec.y));
    }
    for (int i = nstage + tid; i < total; i += 256) {
        int2 rec = csr[bseg + i];
        atomicAdd(&cnt[rec.x & 127], 1);
        atomicAdd(&wsum[rec.x & 127], __int_as_float(rec.y));
    }
    __syncthreads();

    // wave 0: 49-element scan, dinv, nodeptr/ncnt
    if (tid < 64) {
        int l = tid;
        int v = (l < NPB) ? cnt[l] : 0;
        int incl = v;
        for (int off = 1; off < 64; off <<= 1) {
            int t = __shfl_up(incl, off);
            if (l >= off) incl += t;
        }
        int excl = incl - v;
        if (l < NPB) {
            cur[l] = excl;
            float d = rsqrtf(wsum[l]);
            dl[l] = d;
            int n = c0 + l;
            if (n < N_NODES) {
                dinv[n] = d;
                nodeptr[n] = ovf ? bseg : (bseg + excl);
                ncnt[n] = ovf ? -total : v;
            }
        }
    }
    __syncthreads();

    // in-place scatter (all reads were staged before this point)
    if (!ovf) {
        for (int i = tid; i < total; i += 256) {
            int2 rec = srec[i];
            int pos = atomicAdd(&cur[rec.x & 127], 1);   // LDS atomic
            int2 o;
            o.x = rec.x >> 7;
            o.y = rec.y;
            csr[bseg + pos] = o;
        }
    }

    // g = dinv * h for this bucket's nodes (coalesced)
    for (int i = tid; i < NPB * F_OUT; i += 256) {
        int idx = c0 * F_OUT + i;
        if (idx < N_NODES * F_OUT) g[idx] = dl[i >> 4] * h[idx];
    }
}

// K6: wave per node — register accumulation. NO atomics, NO LDS in the loop.
__global__ void k_pull2(const int* __restrict__ nodeptr,
                        const int* __restrict__ ncnt,
                        const int2* __restrict__ csr,
                        const float* __restrict__ g,
                        const float* __restrict__ dinv,
                        const float* __restrict__ bias,
                        float* __restrict__ out) {
    int n = blockIdx.x * 4 + (threadIdx.x >> 6);
    if (n >= N_NODES) return;
    int lane = threadIdx.x & 63;
    int s = lane >> 4;
    int j = lane & 15;
    int p0 = nodeptr[n];
    int cnt = ncnt[n];
    float bj = bias[j];
    float acc = 0.0f;
    if (cnt >= 0) {
#pragma unroll 4
        for (int i = s; i < cnt; i += 4) {
            int2 rec = csr[p0 + i];
            acc += g[(size_t)rec.x * F_OUT + j] * __int_as_float(rec.y);
        }
    } else {
        // overflow bucket (unsorted, cl still packed) — correct slow path
        int total = -cnt;
        int cl = n - (n / NPB) * NPB;
        for (int i = s; i < total; i += 4) {
            int2 rec = csr[p0 + i];
            if ((rec.x & 127) == cl)
                acc += g[(size_t)(rec.x >> 7) * F_OUT + j] * __int_as_float(rec.y);
        }
    }
    acc += __shfl_xor(acc, 16);
    acc += __shfl_xor(acc, 32);
    if (s == 0) {
        float dn = dinv[n];
        out[(size_t)n * F_OUT + j] = bj + dn * (g[(size_t)n * F_OUT + j] + acc);
    }
}

// ============ fallback path (R4, proven) ============

#define EDGE_BLOCKS_FB ((N_EDGES + 255) / 256)
__global__ void k_init_fb(float* __restrict__ deg) {
    int i = blockIdx.x * blockDim.x + threadIdx.x;
    if (i < N_NODES) deg[i] = 1.0f;
}
__global__ void k_fused_fb(const int* __restrict__ col, const float* __restrict__ ew,
                           float* __restrict__ deg, const float* __restrict__ x,
                           const float* __restrict__ W, float* __restrict__ h) {
    int b3 = blockIdx.x / 3;
    int r3 = blockIdx.x % 3;
    if (r3 < 2) {
        int e = (b3 * 2 + r3) * 256 + threadIdx.x;
        if (e < N_EDGES) atomicAdd(&deg[col[e]], ew[e]);
    } else {
        __shared__ float Ws[F_IN * F_OUT];
        int tid = threadIdx.x;
        for (int i = tid; i < F_IN * F_OUT; i += 256) Ws[i] = W[i];
        __syncthreads();
        int n = b3 * 16 + (tid >> 4);
        int j = tid & 15;
        if (n >= N_NODES) return;
        const float4* xr = (const float4*)(x + (size_t)n * F_IN);
        float acc = 0.0f;
#pragma unroll
        for (int k4 = 0; k4 < F_IN / 4; ++k4) {
            float4 xv = xr[k4];
            int k = k4 * 4;
            acc += xv.x * Ws[(k + 0) * F_OUT + j];
            acc += xv.y * Ws[(k + 1) * F_OUT + j];
            acc += xv.z * Ws[(k + 2) * F_OUT + j];
            acc += xv.w * Ws[(k + 3) * F_OUT + j];
        }
        h[(size_t)n * F_OUT + j] = acc;
    }
}
__global__ void k_final_fb(float* __restrict__ deg, const float* __restrict__ h,
                           const float* __restrict__ b, float* __restrict__ g,
                           float* __restrict__ out) {
    int i = blockIdx.x * blockDim.x + threadIdx.x;
    int n = i >> 4;
    int j = i & 15;
    if (n >= N_NODES) return;
    float d = rsqrtf(deg[n]);
    if (j == 0) deg[n] = d;
    float gg = d * h[i];
    g[i] = gg;
    out[i] = b[j] + d * gg;
}
__global__ void k_scatter_fb(const int* __restrict__ row, const int* __restrict__ col,
                             const float* __restrict__ ew, const float* __restrict__ dinv,
                             const float* __restrict__ g, float* __restrict__ out) {
    long long tid = (long long)blockIdx.x * blockDim.x + threadIdx.x;
    int e = (int)(tid >> 4);
    int j = (int)(tid & 15);
    if (e >= N_EDGES) return;
    int c = col[e];
    float norm = ew[e] * dinv[c];
    atomicAdd(&out[(size_t)c * F_OUT + j], g[(size_t)row[e] * F_OUT + j] * norm);
}

extern "C" void kernel_launch(void* const* d_in, const int* in_sizes, int n_in,
                              void* d_out, int out_size, void* d_ws, size_t ws_size,
                              hipStream_t stream) {
    const float* x  = (const float*)d_in[0];
    const int*   ei = (const int*)d_in[1];   // [2, N_EDGES] int32
    const float* ew = (const float*)d_in[2];
    const float* W  = (const float*)d_in[3];
    const float* b  = (const float*)d_in[4];
    float* out = (float*)d_out;

    const int* row = ei;            // edge_index[0] = source
    const int* col = ei + N_EDGES;  // edge_index[1] = destination

    char* ws = (char*)d_ws;
    dim3 blk(256);

    if (ws_size >= WS_NEEDED) {
        int*   ncnt = (int*)(ws + OFF_NCNT);
        int*   tot  = (int*)(ws + OFF_TOT);
        int*   base = (int*)(ws + OFF_BASE);
        float* dinv = (float*)(ws + OFF_DINV);
        int*   nptr = (int*)(ws + OFF_NPTR);
        float* h    = (float*)(ws + OFF_HH);
        float* g    = (float*)(ws + OFF_GG);
        int*   Tt   = (int*)(ws + OFF_TT);      // aliases g (dead before k_sort)
        int2*  csr  = (int2*)(ws + OFF_CSR);

        k_hist_gemm<<<NSEG + GEMM_BLOCKS, blk, 0, stream>>>(col, Tt, x, W, h);
        k_scan_a<<<NBUCK / 4, blk, 0, stream>>>(Tt, tot);
        k_scan_b<<<1, blk, 0, stream>>>(tot, base);
        k_bin<<<NSEG, 512, 0, stream>>>(row, col, ew, Tt, base, csr);
        k_sort<<<NBUCK, blk, 0, stream>>>(base, tot, csr, h, dinv, g, nptr, ncnt);
        k_pull2<<<(N_NODES + 3) / 4, blk, 0, stream>>>(nptr, ncnt, csr, g, dinv, b, out);
    } else {
        float* deg = (float*)ws;
        float* h   = (float*)(ws + (1u << 20));
        float* g   = (float*)(ws + (8u << 20));
        k_init_fb<<<(N_NODES + 255) / 256, blk, 0, stream>>>(deg);
        k_fused_fb<<<EDGE_BLOCKS_FB + GEMM_BLOCKS, blk, 0, stream>>>(col, ew, deg, x, W, h);
        k_final_fb<<<(N_NODES * F_OUT + 255) / 256, blk, 0, stream>>>(deg, h, b, g, out);
        long long total = (long long)N_EDGES * F_OUT;
        k_scatter_fb<<<(unsigned)((total + 255) / 256), blk, 0, stream>>>(row, col, ew, deg, g, out);
    }
}

// Round 10
// 272.836 us; speedup vs baseline: 1.1562x; 1.1562x over previous
//
#include <hip/hip_runtime.h>

#define N_NODES 100000
#define N_EDGES 3200000
#define F_IN 128
#define F_OUT 16

#define NSEG 512                 // binning segments
#define EPS (N_EDGES / NSEG)     // 6250 edges/segment (exact)
#define NBUCK 512                // destination buckets (R10: 2048->512, line-sized runs)
#define NPB 196                  // nodes per bucket: 196*512 = 100352 >= N
#define GEMM_BLOCKS ((N_NODES + 15) / 16)   // 6250
#define MAXREC 7424              // staged records per bucket (mean 6250, +15 sigma)
#define CLMASK 255               // c_local fits 8 bits (NPB=196)

// ---- ws layout (bytes) ----
// Tt (NBUCK*NSEG ints = 1 MB) ALIASES the g region: g is written only in k_sort,
// strictly after k_bin's last Tt read.
#define OFF_NCNT  0u            // N ints (400 KB), written by k_sort
#define OFF_TOT   0x200000u     // NBUCK ints
#define OFF_BASE  0x202000u     // NBUCK ints
#define OFF_DINV  0x210000u     // N floats (400 KB)
#define OFF_NPTR  0x280000u     // N ints (400 KB)
#define OFF_HH    0x300000u     // N*16 floats (6.4 MB)
#define OFF_GG    0x920000u     // N*16 floats (6.4 MB)
#define OFF_TT    0x920000u     // aliases GG (1 MB < 6.4 MB available)
#define OFF_CSR   0x1000000u    // E int2 (25.6 MB); sorted IN PLACE by k_sort
#define WS_NEEDED ((size_t)0x1000000 + (size_t)N_EDGES * 8)

// ============ main path (no global atomics) ============

// K1: per-segment LDS histogram of dest buckets  +  co-scheduled h = x@W
__global__ void k_hist_gemm(const int* __restrict__ col,
                            int* __restrict__ Tt,
                            const float* __restrict__ x,
                            const float* __restrict__ W,
                            float* __restrict__ h) {
    __shared__ int smem[2048];   // hist bins (512 used) OR 8KB W staging
    int tid = threadIdx.x;
    if (blockIdx.x < NSEG) {
        int s = blockIdx.x;
        for (int i = tid; i < NBUCK; i += 256) smem[i] = 0;
        __syncthreads();
        int e0 = s * EPS;
        for (int i = tid; i < EPS; i += 256)
            atomicAdd(&smem[col[e0 + i] / NPB], 1);
        __syncthreads();
        for (int i = tid; i < NBUCK; i += 256)
            Tt[(size_t)i * NSEG + s] = smem[i];
    } else {
        float* Ws = (float*)smem;
        for (int i = tid; i < F_IN * F_OUT; i += 256) Ws[i] = W[i];
        __syncthreads();
        int n = (blockIdx.x - NSEG) * 16 + (tid >> 4);
        int j = tid & 15;
        if (n >= N_NODES) return;
        const float4* xr = (const float4*)(x + (size_t)n * F_IN);
        float acc = 0.0f;
#pragma unroll
        for (int k4 = 0; k4 < F_IN / 4; ++k4) {
            float4 xv = xr[k4];
            int k = k4 * 4;
            acc += xv.x * Ws[(k + 0) * F_OUT + j];
            acc += xv.y * Ws[(k + 1) * F_OUT + j];
            acc += xv.z * Ws[(k + 2) * F_OUT + j];
            acc += xv.w * Ws[(k + 3) * F_OUT + j];
        }
        h[(size_t)n * F_OUT + j] = acc;
    }
}

// K2: wave per bucket — exclusive scan of its NSEG=512 counts (two 256-halves
// with carry, int4 coalesced). Grid: NBUCK/4 blocks of 4 waves.
__global__ void k_scan_a(int* __restrict__ Tt, int* __restrict__ tot) {
    int tid = threadIdx.x;
    int b = blockIdx.x * 4 + (tid >> 6);
    int l = tid & 63;
    int4* row = (int4*)Tt + (size_t)b * (NSEG / 4);
    int4 v0 = row[l];
    int4 v1 = row[l + 64];
    int s0 = v0.x + v0.y + v0.z + v0.w;
    int inc0 = s0;
    for (int off = 1; off < 64; off <<= 1) {
        int t = __shfl_up(inc0, off);
        if (l >= off) inc0 += t;
    }
    int exc0 = inc0 - s0;
    int tot0 = __shfl(inc0, 63);
    int s1 = v1.x + v1.y + v1.z + v1.w;
    int inc1 = s1;
    for (int off = 1; off < 64; off <<= 1) {
        int t = __shfl_up(inc1, off);
        if (l >= off) inc1 += t;
    }
    int exc1 = inc1 - s1 + tot0;
    int4 o0, o1;
    o0.x = exc0;
    o0.y = exc0 + v0.x;
    o0.z = o0.y + v0.y;
    o0.w = o0.z + v0.z;
    o1.x = exc1;
    o1.y = exc1 + v1.x;
    o1.z = o1.y + v1.y;
    o1.w = o1.z + v1.z;
    row[l] = o0;
    row[l + 64] = o1;
    if (l == 63) tot[b] = inc1 + tot0;
}

// K3: single block — exclusive scan of NBUCK=512 totals -> base
__global__ void k_scan_b(const int* __restrict__ tot, int* __restrict__ base) {
    __shared__ int s[256];
    int tid = threadIdx.x;
    const int4* t4 = (const int4*)tot;
    int4 p = (tid < NBUCK / 4) ? t4[tid] : make_int4(0, 0, 0, 0);
    int lsum = p.x + p.y + p.z + p.w;
    s[tid] = lsum;
    __syncthreads();
    for (int off = 1; off < 256; off <<= 1) {
        int t = (tid >= off) ? s[tid - off] : 0;
        __syncthreads();
        s[tid] += t;
        __syncthreads();
    }
    int run = s[tid] - lsum;
    if (tid < NBUCK / 4) {
        int4 o;
        o.x = run; run += p.x;
        o.y = run; run += p.y;
        o.z = run; run += p.z;
        o.w = run;
        ((int4*)base)[tid] = o;
    }
}

// K4: rank-and-write binning. Local hist -> block scan -> rank records into
// LDS in bucket order -> LINEAR write-out (consecutive threads write
// consecutive csr positions; runs avg 12 records -> mostly full-line writes).
__global__ void __launch_bounds__(512) k_bin(const int* __restrict__ row,
                                             const int* __restrict__ col,
                                             const float* __restrict__ ew,
                                             const int* __restrict__ Tt,
                                             const int* __restrict__ base,
                                             int2* __restrict__ csr) {
    __shared__ int2 srec[EPS];        // 50000 B
    __shared__ int lcnt[NBUCK];       // hist, then rank cursors
    __shared__ int lpre[NBUCK + 1];   // exclusive prefix (for search)
    __shared__ int gofs[NBUCK];       // scan temp, then global offset per bucket
    int tid = threadIdx.x;
    int s = blockIdx.x;
    int e0 = s * EPS;

    lcnt[tid] = 0;
    __syncthreads();
    for (int i = tid; i < EPS; i += 512)
        atomicAdd(&lcnt[col[e0 + i] / NPB], 1);
    __syncthreads();

    // block scan (Hillis-Steele over 512, one bucket per thread)
    int v = lcnt[tid];
    gofs[tid] = v;
    __syncthreads();
    for (int off = 1; off < 512; off <<= 1) {
        int t = (tid >= off) ? gofs[tid - off] : 0;
        __syncthreads();
        gofs[tid] += t;
        __syncthreads();
    }
    int excl = gofs[tid] - v;
    lpre[tid] = excl;
    if (tid == 0) lpre[NBUCK] = EPS;
    __syncthreads();
    gofs[tid] = base[tid] + Tt[(size_t)tid * NSEG + s] - excl;
    lcnt[tid] = excl;                  // rank cursor
    __syncthreads();

    // rank & stage into LDS (bucket-ordered)
    for (int i = tid; i < EPS; i += 512) {
        int e = e0 + i;
        int r = row[e];
        int c = col[e];
        int bk = c / NPB;
        int pos = atomicAdd(&lcnt[bk], 1);     // LDS atomic
        int2 rec;
        rec.x = (r << 8) | (c - bk * NPB);
        rec.y = __float_as_int(ew[e]);
        srec[pos] = rec;
    }
    __syncthreads();

    // linear write-out: bucket of slot t via binary search in lpre
    for (int t = tid; t < EPS; t += 512) {
        int lo = 0, hi = NBUCK;
        while (hi - lo > 1) {
            int mid = (lo + hi) >> 1;
            if (lpre[mid] <= t) lo = mid; else hi = mid;
        }
        csr[gofs[lo] + t] = srec[t];
    }
}

// K5: per-bucket — stage slice to LDS; per-node count + weight-sum; scan;
// dinv + g = dinv*h; nodeptr/ncnt; IN-PLACE scatter sorted by dest node,
// stripping c_local. Overflow (> MAXREC, ~never) flagged via negative ncnt.
__global__ void k_sort(const int* __restrict__ base,
                       const int* __restrict__ tot,
                       int2* __restrict__ csr,
                       const float* __restrict__ h,
                       float* __restrict__ dinv,
                       float* __restrict__ g,
                       int* __restrict__ nodeptr,
                       int* __restrict__ ncnt) {
    __shared__ int2 srec[MAXREC];      // 59392 B
    __shared__ int cnt[256];
    __shared__ float wsum[256];
    __shared__ int cur[256];
    __shared__ float dl[256];
    int tid = threadIdx.x;
    int b = blockIdx.x;
    int c0 = b * NPB;
    int bseg = base[b];
    int total = tot[b];
    bool ovf = (total > MAXREC);
    int nstage = ovf ? MAXREC : total;

    cnt[tid] = 0;
    wsum[tid] = 1.0f;   // self-loop weight
    __syncthreads();

    for (int i = tid; i < nstage; i += 256) {
        int2 rec = csr[bseg + i];
        srec[i] = rec;
        atomicAdd(&cnt[rec.x & CLMASK], 1);
        atomicAdd(&wsum[rec.x & CLMASK], __int_as_float(rec.y));
    }
    for (int i = nstage + tid; i < total; i += 256) {
        int2 rec = csr[bseg + i];
        atomicAdd(&cnt[rec.x & CLMASK], 1);
        atomicAdd(&wsum[rec.x & CLMASK], __int_as_float(rec.y));
    }
    __syncthreads();

    // wave 0: scan of 256 counters, lane owns 4; dinv, nodeptr/ncnt
    if (tid < 64) {
        int l = tid;
        int a0 = cnt[4 * l], a1 = cnt[4 * l + 1], a2 = cnt[4 * l + 2], a3 = cnt[4 * l + 3];
        int ssum = a0 + a1 + a2 + a3;
        int incl = ssum;
        for (int off = 1; off < 64; off <<= 1) {
            int t = __shfl_up(incl, off);
            if (l >= off) incl += t;
        }
        int run = incl - ssum;
        int av[4] = {a0, a1, a2, a3};
        for (int k = 0; k < 4; ++k) {
            int bin = 4 * l + k;
            cur[bin] = run;
            float d = rsqrtf(wsum[bin]);
            dl[bin] = d;
            int n = c0 + bin;
            if (bin < NPB && n < N_NODES) {
                dinv[n] = d;
                nodeptr[n] = ovf ? bseg : (bseg + run);
                ncnt[n] = ovf ? -total : av[k];
            }
            run += av[k];
        }
    }
    __syncthreads();

    // in-place scatter (all reads staged before this point); block-local region
    if (!ovf) {
        for (int i = tid; i < total; i += 256) {
            int2 rec = srec[i];
            int pos = atomicAdd(&cur[rec.x & CLMASK], 1);   // LDS atomic
            int2 o;
            o.x = rec.x >> 8;
            o.y = rec.y;
            csr[bseg + pos] = o;
        }
    }

    // g = dinv * h for this bucket's nodes (coalesced)
    for (int i = tid; i < NPB * F_OUT; i += 256) {
        int idx = c0 * F_OUT + i;
        if (idx < N_NODES * F_OUT) g[idx] = dl[i >> 4] * h[idx];
    }
}

// K6: wave per node — register accumulation. NO atomics, NO LDS in the loop.
__global__ void k_pull2(const int* __restrict__ nodeptr,
                        const int* __restrict__ ncnt,
                        const int2* __restrict__ csr,
                        const float* __restrict__ g,
                        const float* __restrict__ dinv,
                        const float* __restrict__ bias,
                        float* __restrict__ out) {
    int n = blockIdx.x * 4 + (threadIdx.x >> 6);
    if (n >= N_NODES) return;
    int lane = threadIdx.x & 63;
    int s = lane >> 4;
    int j = lane & 15;
    int p0 = nodeptr[n];
    int cnt = ncnt[n];
    float bj = bias[j];
    float acc = 0.0f;
    if (cnt >= 0) {
#pragma unroll 4
        for (int i = s; i < cnt; i += 4) {
            int2 rec = csr[p0 + i];
            acc += g[(size_t)rec.x * F_OUT + j] * __int_as_float(rec.y);
        }
    } else {
        // overflow bucket (unsorted, cl still packed) — correct slow path
        int total = -cnt;
        int cl = n - (n / NPB) * NPB;
        for (int i = s; i < total; i += 4) {
            int2 rec = csr[p0 + i];
            if ((rec.x & CLMASK) == cl)
                acc += g[(size_t)(rec.x >> 8) * F_OUT + j] * __int_as_float(rec.y);
        }
    }
    acc += __shfl_xor(acc, 16);
    acc += __shfl_xor(acc, 32);
    if (s == 0) {
        float dn = dinv[n];
        out[(size_t)n * F_OUT + j] = bj + dn * (g[(size_t)n * F_OUT + j] + acc);
    }
}

// ============ fallback path (R4, proven) ============

#define EDGE_BLOCKS_FB ((N_EDGES + 255) / 256)
__global__ void k_init_fb(float* __restrict__ deg) {
    int i = blockIdx.x * blockDim.x + threadIdx.x;
    if (i < N_NODES) deg[i] = 1.0f;
}
__global__ void k_fused_fb(const int* __restrict__ col, const float* __restrict__ ew,
                           float* __restrict__ deg, const float* __restrict__ x,
                           const float* __restrict__ W, float* __restrict__ h) {
    int b3 = blockIdx.x / 3;
    int r3 = blockIdx.x % 3;
    if (r3 < 2) {
        int e = (b3 * 2 + r3) * 256 + threadIdx.x;
        if (e < N_EDGES) atomicAdd(&deg[col[e]], ew[e]);
    } else {
        __shared__ float Ws[F_IN * F_OUT];
        int tid = threadIdx.x;
        for (int i = tid; i < F_IN * F_OUT; i += 256) Ws[i] = W[i];
        __syncthreads();
        int n = b3 * 16 + (tid >> 4);
        int j = tid & 15;
        if (n >= N_NODES) return;
        const float4* xr = (const float4*)(x + (size_t)n * F_IN);
        float acc = 0.0f;
#pragma unroll
        for (int k4 = 0; k4 < F_IN / 4; ++k4) {
            float4 xv = xr[k4];
            int k = k4 * 4;
            acc += xv.x * Ws[(k + 0) * F_OUT + j];
            acc += xv.y * Ws[(k + 1) * F_OUT + j];
            acc += xv.z * Ws[(k + 2) * F_OUT + j];
            acc += xv.w * Ws[(k + 3) * F_OUT + j];
        }
        h[(size_t)n * F_OUT + j] = acc;
    }
}
__global__ void k_final_fb(float* __restrict__ deg, const float* __restrict__ h,
                           const float* __restrict__ b, float* __restrict__ g,
                           float* __restrict__ out) {
    int i = blockIdx.x * blockDim.x + threadIdx.x;
    int n = i >> 4;
    int j = i & 15;
    if (n >= N_NODES) return;
    float d = rsqrtf(deg[n]);
    if (j == 0) deg[n] = d;
    float gg = d * h[i];
    g[i] = gg;
    out[i] = b[j] + d * gg;
}
__global__ void k_scatter_fb(const int* __restrict__ row, const int* __restrict__ col,
                             const float* __restrict__ ew, const float* __restrict__ dinv,
                             const float* __restrict__ g, float* __restrict__ out) {
    long long tid = (long long)blockIdx.x * blockDim.x + threadIdx.x;
    int e = (int)(tid >> 4);
    int j = (int)(tid & 15);
    if (e >= N_EDGES) return;
    int c = col[e];
    float norm = ew[e] * dinv[c];
    atomicAdd(&out[(size_t)c * F_OUT + j], g[(size_t)row[e] * F_OUT + j] * norm);
}

extern "C" void kernel_launch(void* const* d_in, const int* in_sizes, int n_in,
                              void* d_out, int out_size, void* d_ws, size_t ws_size,
                              hipStream_t stream) {
    const float* x  = (const float*)d_in[0];
    const int*   ei = (const int*)d_in[1];   // [2, N_EDGES] int32
    const float* ew = (const float*)d_in[2];
    const float* W  = (const float*)d_in[3];
    const float* b  = (const float*)d_in[4];
    float* out = (float*)d_out;

    const int* row = ei;            // edge_index[0] = source
    const int* col = ei + N_EDGES;  // edge_index[1] = destination

    char* ws = (char*)d_ws;
    dim3 blk(256);

    if (ws_size >= WS_NEEDED) {
        int*   ncnt = (int*)(ws + OFF_NCNT);
        int*   tot  = (int*)(ws + OFF_TOT);
        int*   base = (int*)(ws + OFF_BASE);
        float* dinv = (float*)(ws + OFF_DINV);
        int*   nptr = (int*)(ws + OFF_NPTR);
        float* h    = (float*)(ws + OFF_HH);
        float* g    = (float*)(ws + OFF_GG);
        int*   Tt   = (int*)(ws + OFF_TT);      // aliases g (dead before k_sort)
        int2*  csr  = (int2*)(ws + OFF_CSR);

        k_hist_gemm<<<NSEG + GEMM_BLOCKS, blk, 0, stream>>>(col, Tt, x, W, h);
        k_scan_a<<<NBUCK / 4, blk, 0, stream>>>(Tt, tot);
        k_scan_b<<<1, blk, 0, stream>>>(tot, base);
        k_bin<<<NSEG, 512, 0, stream>>>(row, col, ew, Tt, base, csr);
        k_sort<<<NBUCK, blk, 0, stream>>>(base, tot, csr, h, dinv, g, nptr, ncnt);
        k_pull2<<<(N_NODES + 3) / 4, blk, 0, stream>>>(nptr, ncnt, csr, g, dinv, b, out);
    } else {
        float* deg = (float*)ws;
        float* h   = (float*)(ws + (1u << 20));
        float* g   = (float*)(ws + (8u << 20));
        k_init_fb<<<(N_NODES + 255) / 256, blk, 0, stream>>>(deg);
        k_fused_fb<<<EDGE_BLOCKS_FB + GEMM_BLOCKS, blk, 0, stream>>>(col, ew, deg, x, W, h);
        k_final_fb<<<(N_NODES * F_OUT + 255) / 256, blk, 0, stream>>>(deg, h, b, g, out);
        long long total = (long long)N_EDGES * F_OUT;
        k_scatter_fb<<<(unsigned)((total + 255) / 256), blk, 0, stream>>>(row, col, ew, deg, g, out);
    }
}

// Round 11
// 270.142 us; speedup vs baseline: 1.1678x; 1.0100x over previous
//
#include <hip/hip_runtime.h>

#define N_NODES 100000
#define N_EDGES 3200000
#define F_IN 128
#define F_OUT 16

#define NSEG 512                 // binning segments
#define EPS (N_EDGES / NSEG)     // 6250 edges/segment (exact)
#define NBUCK 512                // destination buckets
#define NPB 196                  // nodes per bucket: 196*512 = 100352 >= N
#define GEMM_BLOCKS ((N_NODES + 15) / 16)   // 6250
#define MAXREC 7424              // staged records per bucket (mean 6250, +15 sigma)
#define CLMASK 255               // c_local fits 8 bits (NPB=196)

// ---- ws layout (bytes) ----
// Tt (NBUCK*NSEG ints = 1 MB) ALIASES the g region (g written only in k_sort,
// strictly after k_bin's last Tt read). g is now bf16 (ushort): 3.2 MB.
#define OFF_NCNT  0u            // N ints (400 KB), written by k_sort
#define OFF_TOT   0x200000u     // NBUCK ints
#define OFF_BASE  0x202000u     // NBUCK ints
#define OFF_DINV  0x210000u     // N floats (400 KB)
#define OFF_NPTR  0x280000u     // N ints (400 KB)
#define OFF_HH    0x300000u     // N*16 floats (6.4 MB)
#define OFF_GG    0x920000u     // N*16 ushorts (3.2 MB), bf16
#define OFF_TT    0x920000u     // aliases GG (1 MB < 3.2 MB)
#define OFF_CSR   0x1000000u    // E int2 (25.6 MB); sorted IN PLACE by k_sort
#define WS_NEEDED ((size_t)0x1000000 + (size_t)N_EDGES * 8)

__device__ __forceinline__ unsigned short f2bf(float f) {
    unsigned u = __float_as_uint(f);
    unsigned r = (u + 0x7FFFu + ((u >> 16) & 1u)) >> 16;   // RNE
    return (unsigned short)r;
}
__device__ __forceinline__ float bf2f(unsigned short v) {
    return __uint_as_float((unsigned)v << 16);
}

// ============ main path (no global atomics) ============

// K1: per-segment LDS histogram of dest buckets  +  co-scheduled h = x@W
__global__ void k_hist_gemm(const int* __restrict__ col,
                            int* __restrict__ Tt,
                            const float* __restrict__ x,
                            const float* __restrict__ W,
                            float* __restrict__ h) {
    __shared__ int smem[2048];   // hist bins (512 used) OR 8KB W staging
    int tid = threadIdx.x;
    if (blockIdx.x < NSEG) {
        int s = blockIdx.x;
        for (int i = tid; i < NBUCK; i += 256) smem[i] = 0;
        __syncthreads();
        int e0 = s * EPS;
        for (int i = tid; i < EPS; i += 256)
            atomicAdd(&smem[col[e0 + i] / NPB], 1);
        __syncthreads();
        for (int i = tid; i < NBUCK; i += 256)
            Tt[(size_t)i * NSEG + s] = smem[i];
    } else {
        float* Ws = (float*)smem;
        for (int i = tid; i < F_IN * F_OUT; i += 256) Ws[i] = W[i];
        __syncthreads();
        int n = (blockIdx.x - NSEG) * 16 + (tid >> 4);
        int j = tid & 15;
        if (n >= N_NODES) return;
        const float4* xr = (const float4*)(x + (size_t)n * F_IN);
        float acc = 0.0f;
#pragma unroll
        for (int k4 = 0; k4 < F_IN / 4; ++k4) {
            float4 xv = xr[k4];
            int k = k4 * 4;
            acc += xv.x * Ws[(k + 0) * F_OUT + j];
            acc += xv.y * Ws[(k + 1) * F_OUT + j];
            acc += xv.z * Ws[(k + 2) * F_OUT + j];
            acc += xv.w * Ws[(k + 3) * F_OUT + j];
        }
        h[(size_t)n * F_OUT + j] = acc;
    }
}

// K2: wave per bucket — exclusive scan of its NSEG=512 counts
__global__ void k_scan_a(int* __restrict__ Tt, int* __restrict__ tot) {
    int tid = threadIdx.x;
    int b = blockIdx.x * 4 + (tid >> 6);
    int l = tid & 63;
    int4* row = (int4*)Tt + (size_t)b * (NSEG / 4);
    int4 v0 = row[l];
    int4 v1 = row[l + 64];
    int s0 = v0.x + v0.y + v0.z + v0.w;
    int inc0 = s0;
    for (int off = 1; off < 64; off <<= 1) {
        int t = __shfl_up(inc0, off);
        if (l >= off) inc0 += t;
    }
    int exc0 = inc0 - s0;
    int tot0 = __shfl(inc0, 63);
    int s1 = v1.x + v1.y + v1.z + v1.w;
    int inc1 = s1;
    for (int off = 1; off < 64; off <<= 1) {
        int t = __shfl_up(inc1, off);
        if (l >= off) inc1 += t;
    }
    int exc1 = inc1 - s1 + tot0;
    int4 o0, o1;
    o0.x = exc0;
    o0.y = exc0 + v0.x;
    o0.z = o0.y + v0.y;
    o0.w = o0.z + v0.z;
    o1.x = exc1;
    o1.y = exc1 + v1.x;
    o1.z = o1.y + v1.y;
    o1.w = o1.z + v1.z;
    row[l] = o0;
    row[l + 64] = o1;
    if (l == 63) tot[b] = inc1 + tot0;
}

// K3: single block — exclusive scan of NBUCK=512 totals -> base
__global__ void k_scan_b(const int* __restrict__ tot, int* __restrict__ base) {
    __shared__ int s[256];
    int tid = threadIdx.x;
    const int4* t4 = (const int4*)tot;
    int4 p = (tid < NBUCK / 4) ? t4[tid] : make_int4(0, 0, 0, 0);
    int lsum = p.x + p.y + p.z + p.w;
    s[tid] = lsum;
    __syncthreads();
    for (int off = 1; off < 256; off <<= 1) {
        int t = (tid >= off) ? s[tid - off] : 0;
        __syncthreads();
        s[tid] += t;
        __syncthreads();
    }
    int run = s[tid] - lsum;
    if (tid < NBUCK / 4) {
        int4 o;
        o.x = run; run += p.x;
        o.y = run; run += p.y;
        o.z = run; run += p.z;
        o.w = run;
        ((int4*)base)[tid] = o;
    }
}

// K4: rank-and-write binning: hist -> scan -> rank into LDS -> linear write-out
__global__ void __launch_bounds__(512) k_bin(const int* __restrict__ row,
                                             const int* __restrict__ col,
                                             const float* __restrict__ ew,
                                             const int* __restrict__ Tt,
                                             const int* __restrict__ base,
                                             int2* __restrict__ csr) {
    __shared__ int2 srec[EPS];        // 50000 B
    __shared__ int lcnt[NBUCK];
    __shared__ int lpre[NBUCK + 1];
    __shared__ int gofs[NBUCK];
    int tid = threadIdx.x;
    int s = blockIdx.x;
    int e0 = s * EPS;

    lcnt[tid] = 0;
    __syncthreads();
    for (int i = tid; i < EPS; i += 512)
        atomicAdd(&lcnt[col[e0 + i] / NPB], 1);
    __syncthreads();

    int v = lcnt[tid];
    gofs[tid] = v;
    __syncthreads();
    for (int off = 1; off < 512; off <<= 1) {
        int t = (tid >= off) ? gofs[tid - off] : 0;
        __syncthreads();
        gofs[tid] += t;
        __syncthreads();
    }
    int excl = gofs[tid] - v;
    lpre[tid] = excl;
    if (tid == 0) lpre[NBUCK] = EPS;
    __syncthreads();
    gofs[tid] = base[tid] + Tt[(size_t)tid * NSEG + s] - excl;
    lcnt[tid] = excl;
    __syncthreads();

    for (int i = tid; i < EPS; i += 512) {
        int e = e0 + i;
        int r = row[e];
        int c = col[e];
        int bk = c / NPB;
        int pos = atomicAdd(&lcnt[bk], 1);     // LDS atomic
        int2 rec;
        rec.x = (r << 8) | (c - bk * NPB);
        rec.y = __float_as_int(ew[e]);
        srec[pos] = rec;
    }
    __syncthreads();

    for (int t = tid; t < EPS; t += 512) {
        int lo = 0, hi = NBUCK;
        while (hi - lo > 1) {
            int mid = (lo + hi) >> 1;
            if (lpre[mid] <= t) lo = mid; else hi = mid;
        }
        csr[gofs[lo] + t] = srec[t];
    }
}

// K5: per-bucket — stage, per-node count/weight-sum, scan, dinv, g=bf16(dinv*h),
// nodeptr/ncnt, in-place node-sort. Overflow flagged via negative ncnt.
__global__ void k_sort(const int* __restrict__ base,
                       const int* __restrict__ tot,
                       int2* __restrict__ csr,
                       const float* __restrict__ h,
                       float* __restrict__ dinv,
                       unsigned short* __restrict__ gb,
                       int* __restrict__ nodeptr,
                       int* __restrict__ ncnt) {
    __shared__ int2 srec[MAXREC];      // 59392 B
    __shared__ int cnt[256];
    __shared__ float wsum[256];
    __shared__ int cur[256];
    __shared__ float dl[256];
    int tid = threadIdx.x;
    int b = blockIdx.x;
    int c0 = b * NPB;
    int bseg = base[b];
    int total = tot[b];
    bool ovf = (total > MAXREC);
    int nstage = ovf ? MAXREC : total;

    cnt[tid] = 0;
    wsum[tid] = 1.0f;   // self-loop weight
    __syncthreads();

    for (int i = tid; i < nstage; i += 256) {
        int2 rec = csr[bseg + i];
        srec[i] = rec;
        atomicAdd(&cnt[rec.x & CLMASK], 1);
        atomicAdd(&wsum[rec.x & CLMASK], __int_as_float(rec.y));
    }
    for (int i = nstage + tid; i < total; i += 256) {
        int2 rec = csr[bseg + i];
        atomicAdd(&cnt[rec.x & CLMASK], 1);
        atomicAdd(&wsum[rec.x & CLMASK], __int_as_float(rec.y));
    }
    __syncthreads();

    if (tid < 64) {
        int l = tid;
        int a0 = cnt[4 * l], a1 = cnt[4 * l + 1], a2 = cnt[4 * l + 2], a3 = cnt[4 * l + 3];
        int ssum = a0 + a1 + a2 + a3;
        int incl = ssum;
        for (int off = 1; off < 64; off <<= 1) {
            int t = __shfl_up(incl, off);
            if (l >= off) incl += t;
        }
        int run = incl - ssum;
        int av[4] = {a0, a1, a2, a3};
        for (int k = 0; k < 4; ++k) {
            int bin = 4 * l + k;
            cur[bin] = run;
            float d = rsqrtf(wsum[bin]);
            dl[bin] = d;
            int n = c0 + bin;
            if (bin < NPB && n < N_NODES) {
                dinv[n] = d;
                nodeptr[n] = ovf ? bseg : (bseg + run);
                ncnt[n] = ovf ? -total : av[k];
            }
            run += av[k];
        }
    }
    __syncthreads();

    if (!ovf) {
        for (int i = tid; i < total; i += 256) {
            int2 rec = srec[i];
            int pos = atomicAdd(&cur[rec.x & CLMASK], 1);   // LDS atomic
            int2 o;
            o.x = rec.x >> 8;
            o.y = rec.y;
            csr[bseg + pos] = o;
        }
    }

    // g = bf16(dinv * h) for this bucket's nodes (coalesced)
    for (int i = tid; i < NPB * F_OUT; i += 256) {
        int idx = c0 * F_OUT + i;
        if (idx < N_NODES * F_OUT) gb[idx] = f2bf(dl[i >> 4] * h[idx]);
    }
}

// K6: wave per node — register accumulation; g gathers from the bf16 table
// (3.2 MB, L2-resident per XCD). NO atomics, NO LDS in the loop.
__global__ void k_pull2(const int* __restrict__ nodeptr,
                        const int* __restrict__ ncnt,
                        const int2* __restrict__ csr,
                        const unsigned short* __restrict__ gb,
                        const float* __restrict__ dinv,
                        const float* __restrict__ bias,
                        float* __restrict__ out) {
    int n = blockIdx.x * 4 + (threadIdx.x >> 6);
    if (n >= N_NODES) return;
    int lane = threadIdx.x & 63;
    int s = lane >> 4;
    int j = lane & 15;
    int p0 = nodeptr[n];
    int cnt = ncnt[n];
    float bj = bias[j];
    float acc = 0.0f;
    if (cnt >= 0) {
#pragma unroll 4
        for (int i = s; i < cnt; i += 4) {
            int2 rec = csr[p0 + i];
            acc += bf2f(gb[(size_t)rec.x * F_OUT + j]) * __int_as_float(rec.y);
        }
    } else {
        // overflow bucket (unsorted, cl still packed) — correct slow path
        int total = -cnt;
        int cl = n - (n / NPB) * NPB;
        for (int i = s; i < total; i += 4) {
            int2 rec = csr[p0 + i];
            if ((rec.x & CLMASK) == cl)
                acc += bf2f(gb[(size_t)(rec.x >> 8) * F_OUT + j]) * __int_as_float(rec.y);
        }
    }
    acc += __shfl_xor(acc, 16);
    acc += __shfl_xor(acc, 32);
    if (s == 0) {
        float dn = dinv[n];
        float gs = bf2f(gb[(size_t)n * F_OUT + j]);
        out[(size_t)n * F_OUT + j] = bj + dn * (gs + acc);
    }
}

// ============ fallback path (R4, proven; fp32 g) ============

#define EDGE_BLOCKS_FB ((N_EDGES + 255) / 256)
__global__ void k_init_fb(float* __restrict__ deg) {
    int i = blockIdx.x * blockDim.x + threadIdx.x;
    if (i < N_NODES) deg[i] = 1.0f;
}
__global__ void k_fused_fb(const int* __restrict__ col, const float* __restrict__ ew,
                           float* __restrict__ deg, const float* __restrict__ x,
                           const float* __restrict__ W, float* __restrict__ h) {
    int b3 = blockIdx.x / 3;
    int r3 = blockIdx.x % 3;
    if (r3 < 2) {
        int e = (b3 * 2 + r3) * 256 + threadIdx.x;
        if (e < N_EDGES) atomicAdd(&deg[col[e]], ew[e]);
    } else {
        __shared__ float Ws[F_IN * F_OUT];
        int tid = threadIdx.x;
        for (int i = tid; i < F_IN * F_OUT; i += 256) Ws[i] = W[i];
        __syncthreads();
        int n = b3 * 16 + (tid >> 4);
        int j = tid & 15;
        if (n >= N_NODES) return;
        const float4* xr = (const float4*)(x + (size_t)n * F_IN);
        float acc = 0.0f;
#pragma unroll
        for (int k4 = 0; k4 < F_IN / 4; ++k4) {
            float4 xv = xr[k4];
            int k = k4 * 4;
            acc += xv.x * Ws[(k + 0) * F_OUT + j];
            acc += xv.y * Ws[(k + 1) * F_OUT + j];
            acc += xv.z * Ws[(k + 2) * F_OUT + j];
            acc += xv.w * Ws[(k + 3) * F_OUT + j];
        }
        h[(size_t)n * F_OUT + j] = acc;
    }
}
__global__ void k_final_fb(float* __restrict__ deg, const float* __restrict__ h,
                           const float* __restrict__ b, float* __restrict__ g,
                           float* __restrict__ out) {
    int i = blockIdx.x * blockDim.x + threadIdx.x;
    int n = i >> 4;
    int j = i & 15;
    if (n >= N_NODES) return;
    float d = rsqrtf(deg[n]);
    if (j == 0) deg[n] = d;
    float gg = d * h[i];
    g[i] = gg;
    out[i] = b[j] + d * gg;
}
__global__ void k_scatter_fb(const int* __restrict__ row, const int* __restrict__ col,
                             const float* __restrict__ ew, const float* __restrict__ dinv,
                             const float* __restrict__ g, float* __restrict__ out) {
    long long tid = (long long)blockIdx.x * blockDim.x + threadIdx.x;
    int e = (int)(tid >> 4);
    int j = (int)(tid & 15);
    if (e >= N_EDGES) return;
    int c = col[e];
    float norm = ew[e] * dinv[c];
    atomicAdd(&out[(size_t)c * F_OUT + j], g[(size_t)row[e] * F_OUT + j] * norm);
}

extern "C" void kernel_launch(void* const* d_in, const int* in_sizes, int n_in,
                              void* d_out, int out_size, void* d_ws, size_t ws_size,
                              hipStream_t stream) {
    const float* x  = (const float*)d_in[0];
    const int*   ei = (const int*)d_in[1];   // [2, N_EDGES] int32
    const float* ew = (const float*)d_in[2];
    const float* W  = (const float*)d_in[3];
    const float* b  = (const float*)d_in[4];
    float* out = (float*)d_out;

    const int* row = ei;            // edge_index[0] = source
    const int* col = ei + N_EDGES;  // edge_index[1] = destination

    char* ws = (char*)d_ws;
    dim3 blk(256);

    if (ws_size >= WS_NEEDED) {
        int*   ncnt = (int*)(ws + OFF_NCNT);
        int*   tot  = (int*)(ws + OFF_TOT);
        int*   base = (int*)(ws + OFF_BASE);
        float* dinv = (float*)(ws + OFF_DINV);
        int*   nptr = (int*)(ws + OFF_NPTR);
        float* h    = (float*)(ws + OFF_HH);
        unsigned short* gb = (unsigned short*)(ws + OFF_GG);
        int*   Tt   = (int*)(ws + OFF_TT);      // aliases gb (dead before k_sort)
        int2*  csr  = (int2*)(ws + OFF_CSR);

        k_hist_gemm<<<NSEG + GEMM_BLOCKS, blk, 0, stream>>>(col, Tt, x, W, h);
        k_scan_a<<<NBUCK / 4, blk, 0, stream>>>(Tt, tot);
        k_scan_b<<<1, blk, 0, stream>>>(tot, base);
        k_bin<<<NSEG, 512, 0, stream>>>(row, col, ew, Tt, base, csr);
        k_sort<<<NBUCK, blk, 0, stream>>>(base, tot, csr, h, dinv, gb, nptr, ncnt);
        k_pull2<<<(N_NODES + 3) / 4, blk, 0, stream>>>(nptr, ncnt, csr, gb, dinv, b, out);
    } else {
        float* deg = (float*)ws;
        float* h   = (float*)(ws + (1u << 20));
        float* g   = (float*)(ws + (8u << 20));
        k_init_fb<<<(N_NODES + 255) / 256, blk, 0, stream>>>(deg);
        k_fused_fb<<<EDGE_BLOCKS_FB + GEMM_BLOCKS, blk, 0, stream>>>(col, ew, deg, x, W, h);
        k_final_fb<<<(N_NODES * F_OUT + 255) / 256, blk, 0, stream>>>(deg, h, b, g, out);
        long long total = (long long)N_EDGES * F_OUT;
        k_scatter_fb<<<(unsigned)((total + 255) / 256), blk, 0, stream>>>(row, col, ew, deg, g, out);
    }
}